// Round 9
// baseline (510.666 us; speedup 1.0000x reference)
//
#include <hip/hip_runtime.h>
#include <math.h>

#define D    6
#define S    128
#define H    128
#define WIN  16
#define BB   8
#define TT   513
#define NW   32
#define OUTD 10

// ---- device-global scratch ----
__device__ float g_lvl1[BB * NW * D];
__device__ float g_area[BB * NW * D * D];
__device__ float g_h0[BB * S];
__device__ float g_hist[BB * (NW + 1) * S];

__device__ __forceinline__ float sp(float x) {
    return (x > 20.f) ? x : log1pf(expf(x));
}
__device__ __forceinline__ float sigm(float x) {
    return 1.f / (1.f + expf(-x));
}
__device__ __forceinline__ float dot4(float4 a, float4 b, float acc) {
    return fmaf(a.x, b.x, fmaf(a.y, b.y, fmaf(a.z, b.z, fmaf(a.w, b.w, acc))));
}

// ---- LDS layout (float offsets) ----
#define O_W0   0        // [128 r][128 k] fp32 row-major
#define O_W1   16384
#define O_PS   32768    // psum [4 c][6 j][128 r] (3072); aliased psumV [2][768]
#define O_U    35840    // [6][128] tangents U ; later T2
#define O_T    36608    // [6][128] T1 ; later bterm [768]
#define O_V    37376    // [768]
#define O_H    38144    // h double buffer [2][128]
#define O_U1   38400
#define O_U2   38528
#define O_SG1  38656
#define O_SG2  38784
#define O_B0   38912
#define O_B1   39040
#define O_SIG  39168    // [2][44]
#define O_B2   39256    // [768] bv2 staged
#define SMTOT  40024    // 160,096 B  (<= 163,840)

// ---- K2: windowed log-signature + init MLP ----
__global__ __launch_bounds__(256) void k_sig(
        const float* __restrict__ x,
        const float* __restrict__ Wi0, const float* __restrict__ bi0,
        const float* __restrict__ Wi1, const float* __restrict__ bi1,
        const float* __restrict__ Wi2, const float* __restrict__ bi2) {
    const int b = blockIdx.x;
    const int tid = threadIdx.x;
    __shared__ float dxs[NW][WIN][D];
    __shared__ float cums[NW][WIN][D];
    __shared__ float ua[H], ub[H];

    const float* xb = x + (size_t)b * TT * D;

    if (tid < NW * D) {
        int w = tid / D, i = tid % D;
        float run = 0.f;
        float prev = xb[(w * WIN) * D + i];
        for (int k = 0; k < WIN; ++k) {
            float cur = xb[(w * WIN + k + 1) * D + i];
            float d = cur - prev; prev = cur;
            dxs[w][k][i] = d;
            cums[w][k][i] = run;
            run += d;
        }
        g_lvl1[(b * NW + w) * D + i] = run;
    }
    __syncthreads();
    for (int e = tid; e < NW * D * D; e += blockDim.x) {
        int w = e / (D * D); int rem = e % (D * D);
        int i = rem / D, j = rem % D;
        float s = 0.f;
        for (int k = 0; k < WIN; ++k)
            s += cums[w][k][i] * dxs[w][k][j] - cums[w][k][j] * dxs[w][k][i];
        g_area[(b * NW + w) * (D * D) + rem] = 0.5f * s;
    }
    if (tid < H) {
        float z = bi0[tid];
        for (int k = 0; k < D; ++k) z += Wi0[tid * D + k] * xb[k];
        ua[tid] = sp(z);
    }
    __syncthreads();
    if (tid < H) {
        float z = bi1[tid];
        for (int k = 0; k < H; ++k) z += Wi1[tid * H + k] * ua[k];
        ub[tid] = sp(z);
    }
    __syncthreads();
    if (tid < H) {
        float z = bi2[tid];
        for (int k = 0; k < H; ++k) z += Wi2[tid * H + k] * ub[k];
        g_h0[b * S + tid] = z;
    }
}

// ---- W2: 48 NAMED float4 per thread = 3 half-rows (kh=tid&1) ----
#define FOR16(X) X(0) X(1) X(2) X(3) X(4) X(5) X(6) X(7) \
                 X(8) X(9) X(10) X(11) X(12) X(13) X(14) X(15)
#define DECL_ABC(q) float4 wA##q, wB##q, wC##q;
#define LOAD_ABC(q) wA##q = W24[baseA + q]; wB##q = W24[baseB + q]; wC##q = W24[baseC + q];
#define S3_Q(q) { float4 u = U24[q]; \
    acc0 = dot4(wA##q, u, acc0); acc1 = dot4(wB##q, u, acc1); acc2 = dot4(wC##q, u, acc2); }
#define S6_Q(q) { \
    acc0 = dot4(wA##q, TA[q], acc0); acc1 = dot4(wB##q, TB[q], acc1); acc2 = dot4(wC##q, TC[q], acc2); }

// ---- K3: the scan: 512 threads (8 waves, pinned 2 waves/EU -> 256 VGPR budget) ----
__global__ __launch_bounds__(512)
__attribute__((amdgpu_waves_per_eu(2, 2)))
void k_scan(
        const float* __restrict__ bv0, const float* __restrict__ bv1,
        const float* __restrict__ bv2,
        const float* __restrict__ Wv0, const float* __restrict__ Wv1,
        const float* __restrict__ Wv2) {
    __shared__ float sm[SMTOT];
    const int b = blockIdx.x, tid = threadIdx.x;
    const int r   = tid & 127;       // row for W0/W1 psum stages
    const int c4  = tid >> 7;        // k-chunk 0..3
    const int key = r & 7;
    // W2 ownership: k-half and 3 rows
    const int kh = tid & 1;
    const int r0 = tid >> 1, r1 = r0 + 256, r2 = r0 + 512;
    const int jA = tid >> 8, jB = 2 + jA, jC = 4 + jA;   // j-blocks of r0,r1,r2

    // stage W0, W1 into LDS (row-major, verbatim); bv2 into LDS
    {
        float4* d = (float4*)(sm + O_W0);
        const float4* s0 = (const float4*)Wv0;
        const float4* s1 = (const float4*)Wv1;
        for (int i = tid; i < 4096; i += 512) { d[i] = s0[i]; d[4096 + i] = s1[i]; }
        sm[O_B2 + tid] = bv2[tid];
        if (tid < 256) sm[O_B2 + 512 + tid] = bv2[512 + tid];
    }
    // W2 half-rows in 48 named float4 registers
    FOR16(DECL_ABC)
    const float4* W24 = (const float4*)Wv2;   // [768][32]
    const int baseA = r0 * 32 + kh * 16;
    const int baseB = r1 * 32 + kh * 16;
    const int baseC = r2 * 32 + kh * 16;
    FOR16(LOAD_ABC)
    if (tid < 128) {
        sm[O_B0 + tid] = bv0[tid]; sm[O_B1 + tid] = bv1[tid];
        float h0v = g_h0[b * 128 + tid];
        sm[O_H + tid] = h0v;
        g_hist[(b * (NW + 1)) * 128 + tid] = h0v;
    }
    if (tid >= 448) {               // sig for t=0 into buf 0
        int q = tid - 448;
        if (q < 42)
            sm[O_SIG + q] = (q < 6) ? g_lvl1[(b * NW) * 6 + q]
                                    : g_area[(b * NW) * 36 + q - 6];
    }
    __syncthreads();

    const float4* W04 = (const float4*)(sm + O_W0);
    const float4* W14 = (const float4*)(sm + O_W1);

    int p = 0;
    for (int t = 0; t < NW; ++t) {
        // prefetch sig for step t+1 into registers (written at H phase)
        float rsig = 0.f;
        if (tid >= 448) {
            int q = tid - 448;
            if (q < 42 && t + 1 < NW)
                rsig = (q < 6) ? g_lvl1[(b * NW + t + 1) * 6 + q]
                               : g_area[(b * NW + t + 1) * 36 + q - 6];
        }
        const int sb = O_SIG + (t & 1) * 44;

        // ---- S1: psum[c4][0][r] = W0[r, chunk c4] . h ----
        {
            float a = 0.f;
            const float4* H4 = (const float4*)(sm + O_H + p * 128);
            #pragma unroll
            for (int q = 0; q < 8; ++q) {
                int qq = c4 * 8 + (q ^ key);
                a = dot4(W04[r * 32 + qq], H4[qq], a);
            }
            sm[O_PS + (c4 * 6) * 128 + r] = a;
        }
        __syncthreads();
        // ---- R1 ----
        if (tid < 128) {
            float z = sm[O_B0 + tid];
            #pragma unroll
            for (int c = 0; c < 4; ++c) z += sm[O_PS + (c * 6) * 128 + tid];
            sm[O_U1 + tid] = sp(z); sm[O_SG1 + tid] = sigm(z);
        }
        __syncthreads();
        // ---- S2 ----
        {
            float a = 0.f;
            const float4* U14 = (const float4*)(sm + O_U1);
            #pragma unroll
            for (int q = 0; q < 8; ++q) {
                int qq = c4 * 8 + (q ^ key);
                a = dot4(W14[r * 32 + qq], U14[qq], a);
            }
            sm[O_PS + (c4 * 6) * 128 + r] = a;
        }
        __syncthreads();
        // ---- R2 ----
        if (tid < 128) {
            float z = sm[O_B1 + tid];
            #pragma unroll
            for (int c = 0; c < 4; ++c) z += sm[O_PS + (c * 6) * 128 + tid];
            sm[O_U2 + tid] = sp(z); sm[O_SG2 + tid] = sigm(z);
        }
        __syncthreads();
        // ---- S3: psumV[kh][row] for rows r0,r1,r2 (register W2) ----
        {
            float acc0 = 0.f, acc1 = 0.f, acc2 = 0.f;
            const float4* U24 = (const float4*)(sm + O_U2) + kh * 16;
            FOR16(S3_Q)
            sm[O_PS + kh * 768 + r0] = acc0;
            sm[O_PS + kh * 768 + r1] = acc1;
            sm[O_PS + kh * 768 + r2] = acc2;
        }
        __syncthreads();
        // ---- R3: V[row] = tanh(b2 + half0 + half1), rows tid and tid+512 ----
        {
            sm[O_V + tid] = tanhf(sm[O_B2 + tid] + sm[O_PS + tid] + sm[O_PS + 768 + tid]);
            if (tid < 256) {
                int e = tid + 512;
                sm[O_V + e] = tanhf(sm[O_B2 + e] + sm[O_PS + e] + sm[O_PS + 768 + e]);
            }
        }
        __syncthreads();
        // ---- UF: U[j][r] = sum_i area[i][j] V[i*128+r]; h-next init ----
        {
            #pragma unroll
            for (int s = 0; s < 2; ++s) {
                int e = tid + s * 512;
                if (s == 0 || tid < 256) {
                    int jj = e >> 7, rr = e & 127;
                    float u = 0.f;
                    #pragma unroll
                    for (int i = 0; i < 6; ++i)
                        u = fmaf(sm[sb + 6 + i * 6 + jj], sm[O_V + i * 128 + rr], u);
                    sm[O_U + jj * 128 + rr] = u;
                }
            }
            if (tid < 128) {
                float xh = sm[O_H + p * 128 + tid];
                #pragma unroll
                for (int i = 0; i < 6; ++i)
                    xh = fmaf(sm[sb + i], sm[O_V + i * 128 + tid], xh);
                sm[O_H + (p ^ 1) * 128 + tid] = xh;
            }
        }
        __syncthreads();
        // ---- S4: psum[c4][j][r] = W0[r, chunk] . U_j ----
        {
            float a0 = 0.f, a1 = 0.f, a2 = 0.f, a3 = 0.f, a4 = 0.f, a5 = 0.f;
            const float4* U4 = (const float4*)(sm + O_U);
            #pragma unroll
            for (int q = 0; q < 8; ++q) {
                int qq = c4 * 8 + (q ^ key);
                float4 w = W04[r * 32 + qq];
                a0 = dot4(w, U4[qq], a0);
                a1 = dot4(w, U4[32 + qq], a1);
                a2 = dot4(w, U4[64 + qq], a2);
                a3 = dot4(w, U4[96 + qq], a3);
                a4 = dot4(w, U4[128 + qq], a4);
                a5 = dot4(w, U4[160 + qq], a5);
            }
            sm[O_PS + (c4 * 6 + 0) * 128 + r] = a0;
            sm[O_PS + (c4 * 6 + 1) * 128 + r] = a1;
            sm[O_PS + (c4 * 6 + 2) * 128 + r] = a2;
            sm[O_PS + (c4 * 6 + 3) * 128 + r] = a3;
            sm[O_PS + (c4 * 6 + 4) * 128 + r] = a4;
            sm[O_PS + (c4 * 6 + 5) * 128 + r] = a5;
        }
        __syncthreads();
        // ---- R4: T1[j][r] = sg1[r] * sum_c ----
        {
            #pragma unroll
            for (int s = 0; s < 2; ++s) {
                int e = tid + s * 512;
                if (s == 0 || tid < 256) {
                    int jj = e >> 7, rr = e & 127;
                    float sv = sm[O_PS + jj * 128 + rr] + sm[O_PS + (6 + jj) * 128 + rr]
                             + sm[O_PS + (12 + jj) * 128 + rr] + sm[O_PS + (18 + jj) * 128 + rr];
                    sm[O_T + jj * 128 + rr] = sm[O_SG1 + rr] * sv;
                }
            }
        }
        __syncthreads();
        // ---- S5: psum[c4][j][r] = W1[r, chunk] . T1_j ----
        {
            float a0 = 0.f, a1 = 0.f, a2 = 0.f, a3 = 0.f, a4 = 0.f, a5 = 0.f;
            const float4* T4 = (const float4*)(sm + O_T);
            #pragma unroll
            for (int q = 0; q < 8; ++q) {
                int qq = c4 * 8 + (q ^ key);
                float4 w = W14[r * 32 + qq];
                a0 = dot4(w, T4[qq], a0);
                a1 = dot4(w, T4[32 + qq], a1);
                a2 = dot4(w, T4[64 + qq], a2);
                a3 = dot4(w, T4[96 + qq], a3);
                a4 = dot4(w, T4[128 + qq], a4);
                a5 = dot4(w, T4[160 + qq], a5);
            }
            sm[O_PS + (c4 * 6 + 0) * 128 + r] = a0;
            sm[O_PS + (c4 * 6 + 1) * 128 + r] = a1;
            sm[O_PS + (c4 * 6 + 2) * 128 + r] = a2;
            sm[O_PS + (c4 * 6 + 3) * 128 + r] = a3;
            sm[O_PS + (c4 * 6 + 4) * 128 + r] = a4;
            sm[O_PS + (c4 * 6 + 5) * 128 + r] = a5;
        }
        __syncthreads();
        // ---- R5: T2[j][r] = sg2[r] * sum_c  (into O_U) ----
        {
            #pragma unroll
            for (int s = 0; s < 2; ++s) {
                int e = tid + s * 512;
                if (s == 0 || tid < 256) {
                    int jj = e >> 7, rr = e & 127;
                    float sv = sm[O_PS + jj * 128 + rr] + sm[O_PS + (6 + jj) * 128 + rr]
                             + sm[O_PS + (12 + jj) * 128 + rr] + sm[O_PS + (18 + jj) * 128 + rr];
                    sm[O_U + jj * 128 + rr] = sm[O_SG2 + rr] * sv;
                }
            }
        }
        __syncthreads();
        // ---- S6: psumV[kh][row] = W2rows . T2_{j(row)} ----
        {
            float acc0 = 0.f, acc1 = 0.f, acc2 = 0.f;
            const float4* TA = (const float4*)(sm + O_U) + jA * 32 + kh * 16;
            const float4* TB = (const float4*)(sm + O_U) + jB * 32 + kh * 16;
            const float4* TC = (const float4*)(sm + O_U) + jC * 32 + kh * 16;
            FOR16(S6_Q)
            sm[O_PS + kh * 768 + r0] = acc0;
            sm[O_PS + kh * 768 + r1] = acc1;
            sm[O_PS + kh * 768 + r2] = acc2;
        }
        __syncthreads();
        // ---- R6: bterm[row] = (1-V^2)*(half0+half1) (into O_T) ----
        {
            float v = sm[O_V + tid];
            sm[O_T + tid] = (1.f - v * v) * (sm[O_PS + tid] + sm[O_PS + 768 + tid]);
            if (tid < 256) {
                int e = tid + 512;
                float v2 = sm[O_V + e];
                sm[O_T + e] = (1.f - v2 * v2) * (sm[O_PS + e] + sm[O_PS + 768 + e]);
            }
        }
        __syncthreads();
        // ---- H: h update + hist; write prefetched sig ----
        if (tid < 128) {
            float xh = sm[O_H + (p ^ 1) * 128 + tid];
            #pragma unroll
            for (int j = 0; j < 6; ++j) xh += sm[O_T + j * 128 + tid];
            sm[O_H + (p ^ 1) * 128 + tid] = xh;
            g_hist[(b * (NW + 1) + t + 1) * 128 + tid] = xh;
        }
        if (tid >= 448) {
            int q = tid - 448;
            if (q < 42 && t + 1 < NW)
                sm[O_SIG + ((t + 1) & 1) * 44 + q] = rsig;
        }
        p ^= 1;
        __syncthreads();
    }
}

// ---- K4: readout ----
__global__ __launch_bounds__(384) void k_read(const float* __restrict__ Wr,
                                              const float* __restrict__ br,
                                              float* __restrict__ out) {
    const int b = blockIdx.x, e = threadIdx.x;
    if (e < (NW + 1) * OUTD) {
        int t = e / OUTD, o = e % OUTD;
        float z = br[o];
        const float4* hrow = (const float4*)&g_hist[(b * (NW + 1) + t) * 128];
        const float4* wrow = (const float4*)&Wr[o * 128];
        float z0 = 0, z1 = 0, z2 = 0, z3 = 0;
        #pragma unroll 8
        for (int s4 = 0; s4 < 32; ++s4) {
            float4 hv = hrow[s4]; float4 wv = wrow[s4];
            z0 = fmaf(hv.x, wv.x, z0); z1 = fmaf(hv.y, wv.y, z1);
            z2 = fmaf(hv.z, wv.z, z2); z3 = fmaf(hv.w, wv.w, z3);
        }
        out[(b * (NW + 1) + t) * OUTD + o] = z + ((z0 + z1) + (z2 + z3));
    }
}

extern "C" void kernel_launch(void* const* d_in, const int* in_sizes, int n_in,
                              void* d_out, int out_size, void* d_ws, size_t ws_size,
                              hipStream_t stream) {
    const float* x   = (const float*)d_in[0];
    const float* Wi0 = (const float*)d_in[1];
    const float* bi0 = (const float*)d_in[2];
    const float* Wi1 = (const float*)d_in[3];
    const float* bi1 = (const float*)d_in[4];
    const float* Wi2 = (const float*)d_in[5];
    const float* bi2 = (const float*)d_in[6];
    const float* Wv0 = (const float*)d_in[7];
    const float* bv0 = (const float*)d_in[8];
    const float* Wv1 = (const float*)d_in[9];
    const float* bv1 = (const float*)d_in[10];
    const float* Wv2 = (const float*)d_in[11];
    const float* bv2 = (const float*)d_in[12];
    const float* Wr  = (const float*)d_in[13];
    const float* br  = (const float*)d_in[14];
    float* out = (float*)d_out;

    hipLaunchKernelGGL(k_sig,  dim3(BB), dim3(256), 0, stream,
                       x, Wi0, bi0, Wi1, bi1, Wi2, bi2);
    hipLaunchKernelGGL(k_scan, dim3(BB), dim3(512), 0, stream,
                       bv0, bv1, bv2, Wv0, Wv1, Wv2);
    hipLaunchKernelGGL(k_read, dim3(BB), dim3(384), 0, stream, Wr, br, out);
}

// Round 11
// 491.182 us; speedup vs baseline: 1.0397x; 1.0397x over previous
//
#include <hip/hip_runtime.h>
#include <math.h>

#define D    6
#define S    128
#define H    128
#define WIN  16
#define BB   8
#define TT   513
#define NW   32
#define OUTD 10

// ---- device-global scratch ----
__device__ float g_lvl1[BB * NW * D];
__device__ float g_area[BB * NW * D * D];
__device__ float g_h0[BB * S];
__device__ float g_hist[BB * (NW + 1) * S];

__device__ __forceinline__ float sp(float x) {
    return (x > 20.f) ? x : log1pf(expf(x));
}
__device__ __forceinline__ float sigm(float x) {
    return 1.f / (1.f + expf(-x));
}
__device__ __forceinline__ float dot4(float4 a, float4 b, float acc) {
    return fmaf(a.x, b.x, fmaf(a.y, b.y, fmaf(a.z, b.z, fmaf(a.w, b.w, acc))));
}

// ---- LDS layout (float offsets) ----
#define O_W0   0        // [128 r][128 k] fp32 row-major
#define O_W1   16384    // -> 32768
#define O_U1   32768    // u1 [128]
#define O_SG1  32896
#define O_U2   33024
#define O_SG2  33152
#define O_V    33280    // [768]
#define O_U    34048    // [6][128]: U tangents, then T2
#define O_TB   34816    // [6][128]: T1, then bterm
#define O_H    35584    // h double buffer [2][128]
#define O_B0   35840
#define O_B1   35968
#define O_B2   36096    // [768]
#define O_SIG  36864    // [2][44]
#define SMTOT  36952    // 147,808 B

// ---- K2: windowed log-signature + init MLP ----
__global__ __launch_bounds__(256) void k_sig(
        const float* __restrict__ x,
        const float* __restrict__ Wi0, const float* __restrict__ bi0,
        const float* __restrict__ Wi1, const float* __restrict__ bi1,
        const float* __restrict__ Wi2, const float* __restrict__ bi2) {
    const int b = blockIdx.x;
    const int tid = threadIdx.x;
    __shared__ float dxs[NW][WIN][D];
    __shared__ float cums[NW][WIN][D];
    __shared__ float ua[H], ub[H];

    const float* xb = x + (size_t)b * TT * D;

    if (tid < NW * D) {
        int w = tid / D, i = tid % D;
        float run = 0.f;
        float prev = xb[(w * WIN) * D + i];
        for (int k = 0; k < WIN; ++k) {
            float cur = xb[(w * WIN + k + 1) * D + i];
            float d = cur - prev; prev = cur;
            dxs[w][k][i] = d;
            cums[w][k][i] = run;
            run += d;
        }
        g_lvl1[(b * NW + w) * D + i] = run;
    }
    __syncthreads();
    for (int e = tid; e < NW * D * D; e += blockDim.x) {
        int w = e / (D * D); int rem = e % (D * D);
        int i = rem / D, j = rem % D;
        float s = 0.f;
        for (int k = 0; k < WIN; ++k)
            s += cums[w][k][i] * dxs[w][k][j] - cums[w][k][j] * dxs[w][k][i];
        g_area[(b * NW + w) * (D * D) + rem] = 0.5f * s;
    }
    if (tid < H) {
        float z = bi0[tid];
        for (int k = 0; k < D; ++k) z += Wi0[tid * D + k] * xb[k];
        ua[tid] = sp(z);
    }
    __syncthreads();
    if (tid < H) {
        float z = bi1[tid];
        for (int k = 0; k < H; ++k) z += Wi1[tid * H + k] * ua[k];
        ub[tid] = sp(z);
    }
    __syncthreads();
    if (tid < H) {
        float z = bi2[tid];
        for (int k = 0; k < H; ++k) z += Wi2[tid * H + k] * ub[k];
        g_h0[b * S + tid] = z;
    }
}

// ---- resident W2 block: 16 named float4 (row m, k-half kh) ----
#define FOR16(X) X(0) X(1) X(2) X(3) X(4) X(5) X(6) X(7) \
                 X(8) X(9) X(10) X(11) X(12) X(13) X(14) X(15)
#define DECL_A(q) float4 wA##q;
#define LOAD_A(q) wA##q = W24[baseA + q];
#define C_Q(q) { float4 u = U24[q]; \
    acc0 = dot4(wA##q, u, acc0); \
    acc1 = dot4(Wm1[q], u, acc1); \
    acc2 = dot4(Wm2[q], u, acc2); }
#define G_Q(q) { \
    acc0 = dot4(wA##q, TA[q], acc0); \
    acc1 = dot4(Wm1[q], TJB[q], acc1); \
    acc2 = dot4(Wm2[q], TJC[q], acc2); }

// ---- K3: the scan: 512 threads, 8 barrier-phases/step, shfl reductions ----
__global__ __launch_bounds__(512) void k_scan(
        const float* __restrict__ bv0, const float* __restrict__ bv1,
        const float* __restrict__ bv2,
        const float* __restrict__ Wv0, const float* __restrict__ Wv1,
        const float* __restrict__ Wv2) {
    __shared__ float sm[SMTOT];
    const int b = blockIdx.x, tid = threadIdx.x;
    // A/B matvec roles
    const int r   = tid >> 2;        // row 0..127
    const int sub = tid & 3;         // k-quarter
    const int keyA = r & 7;
    // C/G roles (W2 rows)
    const int kh = tid & 1;          // k-half
    const int m  = tid >> 1;         // 0..255 -> rows m, m+256, m+512
    // E/F roles (2-row x 3-j tile, k-quarter)
    const int rp = tid >> 3, jg = (tid >> 2) & 1, kq = tid & 3;
    const int ra = 2 * rp, rb = ra + 1, j0 = 3 * jg;
    const int keyE = rp & 7;

    // stage W0, W1 (4096 float4 each), biases
    {
        float4* d = (float4*)(sm + O_W0);
        const float4* s0 = (const float4*)Wv0;
        const float4* s1 = (const float4*)Wv1;
        #pragma unroll
        for (int i = 0; i < 8; ++i) { d[tid + i * 512] = s0[tid + i * 512]; }
        #pragma unroll
        for (int i = 0; i < 8; ++i) { d[4096 + tid + i * 512] = s1[tid + i * 512]; }
        sm[O_B2 + tid] = bv2[tid];
        if (tid < 256) sm[O_B2 + 512 + tid] = bv2[512 + tid];
    }
    // resident W2: row m, half kh (16 quads = 64 VGPR)
    FOR16(DECL_A)
    const float4* W24 = (const float4*)Wv2;   // [768][32]
    const int baseA = m * 32 + kh * 16;
    FOR16(LOAD_A)
    const float4* Wm1 = W24 + (m + 256) * 32 + kh * 16;   // streamed rows
    const float4* Wm2 = W24 + (m + 512) * 32 + kh * 16;
    if (tid < 128) {
        sm[O_B0 + tid] = bv0[tid]; sm[O_B1 + tid] = bv1[tid];
        float h0v = g_h0[b * 128 + tid];
        sm[O_H + tid] = h0v;
        g_hist[(b * (NW + 1)) * 128 + tid] = h0v;
    }
    if (tid >= 448) {               // sig for t=0 into buf 0
        int q = tid - 448;
        if (q < 42)
            sm[O_SIG + q] = (q < 6) ? g_lvl1[(b * NW) * 6 + q]
                                    : g_area[(b * NW) * 36 + q - 6];
    }
    __syncthreads();

    const float4* W04 = (const float4*)(sm + O_W0);
    const float4* W14 = (const float4*)(sm + O_W1);

    int p = 0;
    for (int t = 0; t < NW; ++t) {
        // prefetch sig for t+1 (consumed at H-phase write)
        float rsig = 0.f;
        if (tid >= 448) {
            int q = tid - 448;
            if (q < 42 && t + 1 < NW)
                rsig = (q < 6) ? g_lvl1[(b * NW + t + 1) * 6 + q]
                               : g_area[(b * NW + t + 1) * 36 + q - 6];
        }
        const int sb = O_SIG + (t & 1) * 44;

        // ---- A: z1 = W0.h ; u1, sg1 ----
        {
            float a0 = 0.f, a1 = 0.f;
            const float4* H4 = (const float4*)(sm + O_H + p * 128);
            #pragma unroll
            for (int q = 0; q < 8; q += 2) {
                int q0 = sub * 8 + (q ^ keyA);
                int q1 = sub * 8 + ((q + 1) ^ keyA);
                a0 = dot4(W04[r * 32 + q0], H4[q0], a0);
                a1 = dot4(W04[r * 32 + q1], H4[q1], a1);
            }
            float tot = a0 + a1;
            tot += __shfl_xor(tot, 1);
            tot += __shfl_xor(tot, 2);
            if (sub == 0)      sm[O_U1 + r]  = sp(sm[O_B0 + r] + tot);
            else if (sub == 1) sm[O_SG1 + r] = sigm(sm[O_B0 + r] + tot);
        }
        __syncthreads();
        // ---- B: z2 = W1.u1 ; u2, sg2 ----
        {
            float a0 = 0.f, a1 = 0.f;
            const float4* U14 = (const float4*)(sm + O_U1);
            #pragma unroll
            for (int q = 0; q < 8; q += 2) {
                int q0 = sub * 8 + (q ^ keyA);
                int q1 = sub * 8 + ((q + 1) ^ keyA);
                a0 = dot4(W14[r * 32 + q0], U14[q0], a0);
                a1 = dot4(W14[r * 32 + q1], U14[q1], a1);
            }
            float tot = a0 + a1;
            tot += __shfl_xor(tot, 1);
            tot += __shfl_xor(tot, 2);
            if (sub == 0)      sm[O_U2 + r]  = sp(sm[O_B1 + r] + tot);
            else if (sub == 1) sm[O_SG2 + r] = sigm(sm[O_B1 + r] + tot);
        }
        __syncthreads();
        // ---- C: V = tanh(W2.u2 + b2)  (resident + streamed W2) ----
        {
            float acc0 = 0.f, acc1 = 0.f, acc2 = 0.f;
            const float4* U24 = (const float4*)(sm + O_U2) + kh * 16;
            FOR16(C_Q)
            acc0 += __shfl_xor(acc0, 1);
            acc1 += __shfl_xor(acc1, 1);
            acc2 += __shfl_xor(acc2, 1);
            if (kh == 0) {
                sm[O_V + m]       = tanhf(sm[O_B2 + m] + acc0);
                sm[O_V + m + 256] = tanhf(sm[O_B2 + m + 256] + acc1);
            } else {
                sm[O_V + m + 512] = tanhf(sm[O_B2 + m + 512] + acc2);
            }
        }
        __syncthreads();
        // ---- D: U_j = sum_i area[i][j] V_i ; hpart = h + sum_i l1_i V_i ----
        {
            #pragma unroll
            for (int s = 0; s < 2; ++s) {
                int e = tid + s * 512;
                if (s == 0 || tid < 256) {
                    int jj = e >> 7, rr = e & 127;
                    float u = 0.f;
                    #pragma unroll
                    for (int i = 0; i < 6; ++i)
                        u = fmaf(sm[sb + 6 + i * 6 + jj], sm[O_V + i * 128 + rr], u);
                    sm[O_U + jj * 128 + rr] = u;
                }
            }
            if (tid < 128) {
                float xh = sm[O_H + p * 128 + tid];
                #pragma unroll
                for (int i = 0; i < 6; ++i)
                    xh = fmaf(sm[sb + i], sm[O_V + i * 128 + tid], xh);
                sm[O_H + (p ^ 1) * 128 + tid] = xh;
            }
        }
        __syncthreads();
        // ---- E: T1_j = sg1 .* (W0 U_j)   2-row x 3-j tile, k-quarter ----
        {
            float aa0=0,aa1=0,aa2=0, ab0=0,ab1=0,ab2=0;
            const float4* U4 = (const float4*)(sm + O_U);
            #pragma unroll
            for (int q = 0; q < 8; ++q) {
                int qq = kq * 8 + (q ^ keyE);
                float4 wa = W04[ra * 32 + qq], wb = W04[rb * 32 + qq];
                float4 u0 = U4[j0 * 32 + qq], u1 = U4[(j0+1) * 32 + qq], u2 = U4[(j0+2) * 32 + qq];
                aa0 = dot4(wa, u0, aa0); aa1 = dot4(wa, u1, aa1); aa2 = dot4(wa, u2, aa2);
                ab0 = dot4(wb, u0, ab0); ab1 = dot4(wb, u1, ab1); ab2 = dot4(wb, u2, ab2);
            }
            aa0 += __shfl_xor(aa0,1); aa0 += __shfl_xor(aa0,2);
            aa1 += __shfl_xor(aa1,1); aa1 += __shfl_xor(aa1,2);
            aa2 += __shfl_xor(aa2,1); aa2 += __shfl_xor(aa2,2);
            ab0 += __shfl_xor(ab0,1); ab0 += __shfl_xor(ab0,2);
            ab1 += __shfl_xor(ab1,1); ab1 += __shfl_xor(ab1,2);
            ab2 += __shfl_xor(ab2,1); ab2 += __shfl_xor(ab2,2);
            if (kq == 0) {
                float sg = sm[O_SG1 + ra];
                sm[O_TB + j0 * 128 + ra] = sg * aa0;
                sm[O_TB + (j0+1) * 128 + ra] = sg * aa1;
                sm[O_TB + (j0+2) * 128 + ra] = sg * aa2;
            } else if (kq == 1) {
                float sg = sm[O_SG1 + rb];
                sm[O_TB + j0 * 128 + rb] = sg * ab0;
                sm[O_TB + (j0+1) * 128 + rb] = sg * ab1;
                sm[O_TB + (j0+2) * 128 + rb] = sg * ab2;
            }
        }
        __syncthreads();
        // ---- F: T2_j = sg2 .* (W1 T1_j)  (into O_U) ----
        {
            float aa0=0,aa1=0,aa2=0, ab0=0,ab1=0,ab2=0;
            const float4* T4 = (const float4*)(sm + O_TB);
            #pragma unroll
            for (int q = 0; q < 8; ++q) {
                int qq = kq * 8 + (q ^ keyE);
                float4 wa = W14[ra * 32 + qq], wb = W14[rb * 32 + qq];
                float4 u0 = T4[j0 * 32 + qq], u1 = T4[(j0+1) * 32 + qq], u2 = T4[(j0+2) * 32 + qq];
                aa0 = dot4(wa, u0, aa0); aa1 = dot4(wa, u1, aa1); aa2 = dot4(wa, u2, aa2);
                ab0 = dot4(wb, u0, ab0); ab1 = dot4(wb, u1, ab1); ab2 = dot4(wb, u2, ab2);
            }
            aa0 += __shfl_xor(aa0,1); aa0 += __shfl_xor(aa0,2);
            aa1 += __shfl_xor(aa1,1); aa1 += __shfl_xor(aa1,2);
            aa2 += __shfl_xor(aa2,1); aa2 += __shfl_xor(aa2,2);
            ab0 += __shfl_xor(ab0,1); ab0 += __shfl_xor(ab0,2);
            ab1 += __shfl_xor(ab1,1); ab1 += __shfl_xor(ab1,2);
            ab2 += __shfl_xor(ab2,1); ab2 += __shfl_xor(ab2,2);
            if (kq == 0) {
                float sg = sm[O_SG2 + ra];
                sm[O_U + j0 * 128 + ra] = sg * aa0;
                sm[O_U + (j0+1) * 128 + ra] = sg * aa1;
                sm[O_U + (j0+2) * 128 + ra] = sg * aa2;
            } else if (kq == 1) {
                float sg = sm[O_SG2 + rb];
                sm[O_U + j0 * 128 + rb] = sg * ab0;
                sm[O_U + (j0+1) * 128 + rb] = sg * ab1;
                sm[O_U + (j0+2) * 128 + rb] = sg * ab2;
            }
        }
        __syncthreads();
        // ---- G: bterm = (1-V^2).*(W2 T2_j(row))  (into O_TB) ----
        {
            float acc0 = 0.f, acc1 = 0.f, acc2 = 0.f;
            const int jA = m >> 7;
            const float4* TA  = (const float4*)(sm + O_U) + jA * 32 + kh * 16;
            const float4* TJB = (const float4*)(sm + O_U) + (2 + jA) * 32 + kh * 16;
            const float4* TJC = (const float4*)(sm + O_U) + (4 + jA) * 32 + kh * 16;
            FOR16(G_Q)
            acc0 += __shfl_xor(acc0, 1);
            acc1 += __shfl_xor(acc1, 1);
            acc2 += __shfl_xor(acc2, 1);
            if (kh == 0) {
                float v0 = sm[O_V + m];
                float v1 = sm[O_V + m + 256];
                sm[O_TB + m]       = (1.f - v0 * v0) * acc0;
                sm[O_TB + m + 256] = (1.f - v1 * v1) * acc1;
            } else {
                float v2 = sm[O_V + m + 512];
                sm[O_TB + m + 512] = (1.f - v2 * v2) * acc2;
            }
        }
        __syncthreads();
        // ---- H: h update + hist; store prefetched sig ----
        if (tid < 128) {
            float xh = sm[O_H + (p ^ 1) * 128 + tid];
            #pragma unroll
            for (int j = 0; j < 6; ++j) xh += sm[O_TB + j * 128 + tid];
            sm[O_H + (p ^ 1) * 128 + tid] = xh;
            g_hist[(b * (NW + 1) + t + 1) * 128 + tid] = xh;
        }
        if (tid >= 448) {
            int q = tid - 448;
            if (q < 42 && t + 1 < NW)
                sm[O_SIG + ((t + 1) & 1) * 44 + q] = rsig;
        }
        p ^= 1;
        __syncthreads();
    }
}

// ---- K4: readout ----
__global__ __launch_bounds__(384) void k_read(const float* __restrict__ Wr,
                                              const float* __restrict__ br,
                                              float* __restrict__ out) {
    const int b = blockIdx.x, e = threadIdx.x;
    if (e < (NW + 1) * OUTD) {
        int t = e / OUTD, o = e % OUTD;
        float z = br[o];
        const float4* hrow = (const float4*)&g_hist[(b * (NW + 1) + t) * 128];
        const float4* wrow = (const float4*)&Wr[o * 128];
        float z0 = 0, z1 = 0, z2 = 0, z3 = 0;
        #pragma unroll 8
        for (int s4 = 0; s4 < 32; ++s4) {
            float4 hv = hrow[s4]; float4 wv = wrow[s4];
            z0 = fmaf(hv.x, wv.x, z0); z1 = fmaf(hv.y, wv.y, z1);
            z2 = fmaf(hv.z, wv.z, z2); z3 = fmaf(hv.w, wv.w, z3);
        }
        out[(b * (NW + 1) + t) * OUTD + o] = z + ((z0 + z1) + (z2 + z3));
    }
}

extern "C" void kernel_launch(void* const* d_in, const int* in_sizes, int n_in,
                              void* d_out, int out_size, void* d_ws, size_t ws_size,
                              hipStream_t stream) {
    const float* x   = (const float*)d_in[0];
    const float* Wi0 = (const float*)d_in[1];
    const float* bi0 = (const float*)d_in[2];
    const float* Wi1 = (const float*)d_in[3];
    const float* bi1 = (const float*)d_in[4];
    const float* Wi2 = (const float*)d_in[5];
    const float* bi2 = (const float*)d_in[6];
    const float* Wv0 = (const float*)d_in[7];
    const float* bv0 = (const float*)d_in[8];
    const float* Wv1 = (const float*)d_in[9];
    const float* bv1 = (const float*)d_in[10];
    const float* Wv2 = (const float*)d_in[11];
    const float* bv2 = (const float*)d_in[12];
    const float* Wr  = (const float*)d_in[13];
    const float* br  = (const float*)d_in[14];
    float* out = (float*)d_out;

    hipLaunchKernelGGL(k_sig,  dim3(BB), dim3(256), 0, stream,
                       x, Wi0, bi0, Wi1, bi1, Wi2, bi2);
    hipLaunchKernelGGL(k_scan, dim3(BB), dim3(512), 0, stream,
                       bv0, bv1, bv2, Wv0, Wv1, Wv2);
    hipLaunchKernelGGL(k_read, dim3(BB), dim3(384), 0, stream, Wr, br, out);
}